// Round 3
// baseline (1094.318 us; speedup 1.0000x reference)
//
#include <hip/hip_runtime.h>
#include <math.h>
#include <stdint.h>

#define N_Q 32768
#define K_C 8192
#define D_DIM 512
#define NT 48            // K' tiles: 1536 / 32

typedef __attribute__((ext_vector_type(8))) short bf16x8;
typedef __attribute__((ext_vector_type(4))) float f32x4;

typedef const __attribute__((address_space(1))) void gv_t;
typedef __attribute__((address_space(3))) void lv_t;

static __device__ __forceinline__ void gl16(const void* g, void* l) {
    __builtin_amdgcn_global_load_lds((gv_t*)g, (lv_t*)l, 16, 0, 0);
}

static __device__ __forceinline__ unsigned short f2bf(float f) {
    unsigned u = __float_as_uint(f);
    unsigned r = u + 0x7fffu + ((u >> 16) & 1u);
    return (unsigned short)(r >> 16);
}
static __device__ __forceinline__ float bf2f(unsigned short h) {
    return __uint_as_float(((unsigned)h) << 16);
}

// ---------------- kernel 1: normalize emb rows -> wh/wl [k][d] bf16 + wnorm2[k]
__global__ void k_normw(const float* __restrict__ w, unsigned short* __restrict__ wh,
                        unsigned short* __restrict__ wl, float* __restrict__ wnorm2) {
    __shared__ float red[4];
    __shared__ float s_n;
    int k = blockIdx.x;
    int t = threadIdx.x;
    int lane = t & 63, wid = t >> 6;
    float v0 = w[(size_t)k * D_DIM + t];
    float v1 = w[(size_t)k * D_DIM + t + 256];
    float ss = fmaf(v0, v0, v1 * v1);
    for (int off = 32; off; off >>= 1) ss += __shfl_down(ss, off, 64);
    if (lane == 0) red[wid] = ss;
    __syncthreads();
    if (t == 0) s_n = fmaxf(sqrtf(red[0] + red[1] + red[2] + red[3]), 1e-12f);
    __syncthreads();
    float n = s_n;
    float a0 = v0 / n, a1 = v1 / n;
    unsigned short h0 = f2bf(a0), h1 = f2bf(a1);
    wh[(size_t)k * D_DIM + t] = h0;
    wh[(size_t)k * D_DIM + t + 256] = h1;
    wl[(size_t)k * D_DIM + t] = f2bf(a0 - bf2f(h0));
    wl[(size_t)k * D_DIM + t + 256] = f2bf(a1 - bf2f(h1));
    float s2 = fmaf(a0, a0, a1 * a1);
    for (int off = 32; off; off >>= 1) s2 += __shfl_down(s2, off, 64);
    __syncthreads();
    if (lane == 0) red[wid] = s2;
    __syncthreads();
    if (t == 0) wnorm2[k] = red[0] + red[1] + red[2] + red[3];
}

// ---------------- kernel 2: ||x_n|| per row + xh/xl [n][d] bf16
__global__ void k_normx(const float* __restrict__ x, float* __restrict__ xnorm,
                        unsigned short* __restrict__ xh, unsigned short* __restrict__ xl) {
    int wid = threadIdx.x >> 6, lane = threadIdx.x & 63;
    int n = blockIdx.x * 4 + wid;
    const float* xr = x + (size_t)n * D_DIM;
    float v[8];
    float ss = 0.f;
    #pragma unroll
    for (int i = 0; i < 8; ++i) {
        v[i] = xr[lane + i * 64];
        ss = fmaf(v[i], v[i], ss);
    }
    for (int off = 32; off; off >>= 1) ss += __shfl_down(ss, off, 64);
    ss = __shfl(ss, 0, 64);
    float nrm = fmaxf(sqrtf(ss), 1e-12f);
    if (lane == 0) xnorm[n] = nrm;
    #pragma unroll
    for (int i = 0; i < 8; ++i) {
        float a = v[i] / nrm;
        unsigned short h = f2bf(a);
        size_t o = (size_t)n * D_DIM + lane + i * 64;
        xh[o] = h;
        xl[o] = f2bf(a - bf2f(h));
    }
}

// ---------------- k_score tile body (2 phases, counted vmcnt, setprio)
// VMODE: 4 = steady vmcnt(4); 0 = vmcnt(0); -1 = none
template <int DO_STAGE, int VMODE>
static __device__ __forceinline__ void tile_body(
    const char* lbase, char* sdst,
    const unsigned short* pa, const unsigned short* pb,
    const int* aoff, const int* boff, f32x4 (&acc)[8][4])
{
    bf16x8 a0[4], a1[4], b0[4];
    // ---- phase 0: reads a[0-3], b[0-3]; stage A halves of tile t+2
    #pragma unroll
    for (int m = 0; m < 4; ++m) a0[m] = *(const bf16x8*)(lbase + aoff[m]);
    #pragma unroll
    for (int n = 0; n < 4; ++n) b0[n] = *(const bf16x8*)(lbase + 16384 + boff[n]);
    if (DO_STAGE) {
        gl16(pa, sdst);
        gl16(pa + 128 * D_DIM, sdst + 8192);
    }
    asm volatile("s_barrier" ::: "memory");
    asm volatile("s_waitcnt lgkmcnt(0)" ::: "memory");
    __builtin_amdgcn_sched_barrier(0);
    __builtin_amdgcn_s_setprio(1);
    #pragma unroll
    for (int m = 0; m < 4; ++m)
        #pragma unroll
        for (int n = 0; n < 4; ++n)
            acc[m][n] = __builtin_amdgcn_mfma_f32_16x16x32_bf16(a0[m], b0[n], acc[m][n], 0, 0, 0);
    __builtin_amdgcn_s_setprio(0);
    asm volatile("s_barrier" ::: "memory");
    // ---- phase 1: reads a[4-7]; stage B halves of tile t+2
    #pragma unroll
    for (int m = 0; m < 4; ++m) a1[m] = *(const bf16x8*)(lbase + aoff[4 + m]);
    if (DO_STAGE) {
        gl16(pb, sdst + 16384);
        gl16(pb + 128 * D_DIM, sdst + 24576);
    }
    asm volatile("s_barrier" ::: "memory");
    asm volatile("s_waitcnt lgkmcnt(0)" ::: "memory");
    __builtin_amdgcn_sched_barrier(0);
    __builtin_amdgcn_s_setprio(1);
    #pragma unroll
    for (int m = 0; m < 4; ++m)
        #pragma unroll
        for (int n = 0; n < 4; ++n)
            acc[4 + m][n] = __builtin_amdgcn_mfma_f32_16x16x32_bf16(a1[m], b0[n], acc[4 + m][n], 0, 0, 0);
    __builtin_amdgcn_s_setprio(0);
    if (VMODE == 4)      asm volatile("s_waitcnt vmcnt(4)" ::: "memory");
    else if (VMODE == 0) asm volatile("s_waitcnt vmcnt(0)" ::: "memory");
    asm volatile("s_barrier" ::: "memory");
}

// ---------------- kernel 3: MFMA score + per-block argmin partials
// C = A'·B'^T over K'=1536: A' = [Xh|Xh|Xl], B' = [Wh|Wl|Wh] (3-pass hi/lo split).
// BM=BN=256, BK=32, 512 thr = 8 waves (2M x 4N), per-wave 128x64, acc 8x4 frags.
// LDS: 3 rotating buffers x (A 16KB + B 16KB) = 96KB, chunk-swizzled
// phys_chunk = r*4 + (g ^ ((r>>1)&3))  (measured conflict-free in round 2).
__global__ __launch_bounds__(512, 2) void k_score(
    const unsigned short* __restrict__ xh, const unsigned short* __restrict__ xl,
    const unsigned short* __restrict__ wh, const unsigned short* __restrict__ wl,
    const float* __restrict__ wnorm2, unsigned long long* __restrict__ pmin_part)
{
    __shared__ __align__(16) char lds[98304];
    int tid = threadIdx.x;
    int lane = tid & 63, wid = tid >> 6;
    int wm = wid >> 2, wn = wid & 3;
    int k0 = blockIdx.x * 256;      // codes
    int n0 = blockIdx.y * 256;      // x rows
    int c15 = lane & 15, g = lane >> 4;

    // fragment LDS byte offsets (within a region)
    int aoff[8], boff[4];
    #pragma unroll
    for (int m = 0; m < 8; ++m) {
        int r = wm * 128 + m * 16 + c15;
        aoff[m] = (r * 4 + (g ^ ((r >> 1) & 3))) * 16;
    }
    #pragma unroll
    for (int n = 0; n < 4; ++n) {
        int r = wn * 64 + n * 16 + c15;
        boff[n] = (r * 4 + (g ^ ((r >> 1) & 3))) * 16;
    }

    // staging source offsets: physical chunk p -> r = p>>2, g = (p&3)^((p>>3)&3)
    int rs = tid >> 2;
    int gs = (tid & 3) ^ ((tid >> 3) & 3);
    size_t offA = (size_t)(n0 + rs) * D_DIM + gs * 8;
    size_t offB = (size_t)(k0 + rs) * D_DIM + gs * 8;
    char* dst = lds + tid * 16;

    f32x4 acc[8][4];
    #pragma unroll
    for (int m = 0; m < 8; ++m)
        #pragma unroll
        for (int n = 0; n < 4; ++n) acc[m][n] = (f32x4){0.f, 0.f, 0.f, 0.f};

    // prologue: stage tiles 0 (buf0) and 1 (buf1)
    {
        gl16(xh + offA, dst);
        gl16(xh + offA + 128 * D_DIM, dst + 8192);
        gl16(wh + offB, dst + 16384);
        gl16(wh + offB + 128 * D_DIM, dst + 24576);
        gl16(xh + offA + 32, dst + 32768);
        gl16(xh + offA + 32 + 128 * D_DIM, dst + 32768 + 8192);
        gl16(wh + offB + 32, dst + 32768 + 16384);
        gl16(wh + offB + 32 + 128 * D_DIM, dst + 32768 + 24576);
    }
    asm volatile("s_waitcnt vmcnt(4)" ::: "memory");
    asm volatile("s_barrier" ::: "memory");

    unsigned cb0 = 0, cb1 = 32768, cb2 = 65536;
    for (int t = 0; t < NT - 2; ++t) {
        int u = t + 2;
        const unsigned short* pa = ((u < 32) ? xh : xl) + offA + ((u & 15) << 5);
        const unsigned short* pb = ((u < 16 || u >= 32) ? wh : wl) + offB + ((u & 15) << 5);
        tile_body<1, 4>(lds + cb0, dst + cb2, pa, pb, aoff, boff, acc);
        unsigned tmp = cb0; cb0 = cb1; cb1 = cb2; cb2 = tmp;
    }
    tile_body<0, 0>(lds + cb0, dst, (const unsigned short*)0, (const unsigned short*)0, aoff, boff, acc);
    { unsigned tmp = cb0; cb0 = cb1; cb1 = cb2; cb2 = tmp; }
    tile_body<0, -1>(lds + cb0, dst, (const unsigned short*)0, (const unsigned short*)0, aoff, boff, acc);

    // epilogue: dist = wnorm2[k] - 2*dot ; per-row argmin, wn-combined in LDS
    float w2[4];
    #pragma unroll
    for (int n = 0; n < 4; ++n) w2[n] = wnorm2[k0 + wn * 64 + n * 16 + c15];

    unsigned long long* scr = (unsigned long long*)lds;   // 256 rows x 4 wn = 8KB
    #pragma unroll
    for (int m = 0; m < 8; ++m) {
        #pragma unroll
        for (int reg = 0; reg < 4; ++reg) {
            float bv = INFINITY;
            int bk = 0x7fffffff;
            #pragma unroll
            for (int n = 0; n < 4; ++n) {
                float v = fmaf(-2.f, acc[m][n][reg], w2[n]);
                int kk = k0 + wn * 64 + n * 16 + c15;
                if (v < bv || (v == bv && kk < bk)) { bv = v; bk = kk; }
            }
            for (int off = 8; off; off >>= 1) {
                float v2 = __shfl_xor(bv, off, 16);
                int k2 = __shfl_xor(bk, off, 16);
                if (v2 < bv || (v2 == bv && k2 < bk)) { bv = v2; bk = k2; }
            }
            if (c15 == 0) {
                int row = wm * 128 + m * 16 + g * 4 + reg;
                unsigned ub = __float_as_uint(bv);
                ub = (ub & 0x80000000u) ? ~ub : (ub | 0x80000000u);
                scr[row * 4 + wn] = ((unsigned long long)ub << 32) | (unsigned)bk;
            }
        }
    }
    __syncthreads();
    if (tid < 256) {
        unsigned long long v = scr[tid * 4];
        #pragma unroll
        for (int j = 1; j < 4; ++j) {
            unsigned long long u = scr[tid * 4 + j];
            if (u < v) v = u;
        }
        pmin_part[(size_t)blockIdx.x * N_Q + n0 + tid] = v;
    }
}

// ---------------- kernel 4: final argmin reduce over the 32 code-tiles
__global__ void k_argmin(const unsigned long long* __restrict__ part, int* __restrict__ idx) {
    int n = blockIdx.x * 256 + threadIdx.x;
    unsigned long long v = part[n];
    #pragma unroll 4
    for (int j = 1; j < 32; ++j) {
        unsigned long long u = part[(size_t)j * N_Q + n];
        if (u < v) v = u;
    }
    idx[n] = (int)(unsigned)(v & 0xffffffffull);
}

// ---------------- kernel 5: gather quantized rows, write output + idxf, loss partials
__global__ void k_gather(const float* __restrict__ x, const float* __restrict__ emb,
                         const float* __restrict__ xnorm, const int* __restrict__ idx,
                         float* __restrict__ qout, float* __restrict__ idxf,
                         float* __restrict__ partials) {
    __shared__ float red[4];
    int t = threadIdx.x, lane = t & 63, wid = t >> 6;
    int n = blockIdx.x * 4 + wid;
    int k = idx[n];
    const float* er = emb + (size_t)k * D_DIM + lane * 8;
    float4 e0 = *(const float4*)er;
    float4 e1 = *(const float4*)(er + 4);
    float ss = e0.x * e0.x + e0.y * e0.y + e0.z * e0.z + e0.w * e0.w
             + e1.x * e1.x + e1.y * e1.y + e1.z * e1.z + e1.w * e1.w;
    for (int off = 32; off; off >>= 1) ss += __shfl_down(ss, off, 64);
    ss = __shfl(ss, 0, 64);
    float nn = fmaxf(sqrtf(ss), 1e-12f);
    float4 q0, q1;
    q0.x = e0.x / nn; q0.y = e0.y / nn; q0.z = e0.z / nn; q0.w = e0.w / nn;
    q1.x = e1.x / nn; q1.y = e1.y / nn; q1.z = e1.z / nn; q1.w = e1.w / nn;

    const float* xr = x + (size_t)n * D_DIM + lane * 8;
    float4 x0 = *(const float4*)xr;
    float4 x1 = *(const float4*)(xr + 4);
    float xn = xnorm[n];
    float d0 = x0.x / xn - q0.x, d1 = x0.y / xn - q0.y;
    float d2 = x0.z / xn - q0.z, d3 = x0.w / xn - q0.w;
    float d4 = x1.x / xn - q1.x, d5 = x1.y / xn - q1.y;
    float d6 = x1.z / xn - q1.z, d7 = x1.w / xn - q1.w;
    float ds = d0 * d0 + d1 * d1 + d2 * d2 + d3 * d3
             + d4 * d4 + d5 * d5 + d6 * d6 + d7 * d7;

    float* qo = qout + (size_t)n * D_DIM + lane * 8;
    *(float4*)qo = q0;
    *(float4*)(qo + 4) = q1;
    if (lane == 0) idxf[n] = (float)k;

    for (int off = 32; off; off >>= 1) ds += __shfl_down(ds, off, 64);
    if (lane == 0) red[wid] = ds;
    __syncthreads();
    if (t == 0) partials[blockIdx.x] = red[0] + red[1] + red[2] + red[3];
}

// ---------------- kernel 6: deterministic final loss reduction
__global__ void k_loss(const float* __restrict__ partials, float* __restrict__ out_loss) {
    __shared__ float red[4];
    int t = threadIdx.x, lane = t & 63, wid = t >> 6;
    float s = 0.f;
    for (int i = t; i < 8192; i += 256) s += partials[i];
    for (int off = 32; off; off >>= 1) s += __shfl_down(s, off, 64);
    if (lane == 0) red[wid] = s;
    __syncthreads();
    if (t == 0)
        out_loss[0] = (red[0] + red[1] + red[2] + red[3]) * (1.25f / ((float)N_Q * (float)D_DIM));
}

extern "C" void kernel_launch(void* const* d_in, const int* in_sizes, int n_in,
                              void* d_out, int out_size, void* d_ws, size_t ws_size,
                              hipStream_t stream) {
    (void)in_sizes; (void)n_in; (void)out_size; (void)ws_size;
    const float* x = (const float*)d_in[0];
    const float* w = (const float*)d_in[1];

    float* out = (float*)d_out;
    float* qout = out;                                  // N*D f32
    float* loss = out + (size_t)N_Q * D_DIM;            // 1
    float* idxf = loss + 1;                             // N

    // xh/xl scratch lives in the qout region (exactly 2*N*D shorts),
    // consumed by k_score, then overwritten by k_gather's final output.
    unsigned short* xh = (unsigned short*)qout;         // N*D shorts
    unsigned short* xl = xh + (size_t)N_Q * D_DIM;      // N*D shorts

    char* ws = (char*)d_ws;
    unsigned short* wh = (unsigned short*)ws;                       // 8MB
    unsigned short* wl = wh + (size_t)K_C * D_DIM;                  // 8MB
    float* wnorm2 = (float*)(wl + (size_t)K_C * D_DIM);             // 32KB
    float* xnorm = wnorm2 + K_C;                                    // 128KB
    unsigned long long* pmin_part = (unsigned long long*)(xnorm + N_Q);  // 32*N u64 = 8MB
    int* idx = (int*)(pmin_part + (size_t)32 * N_Q);                // 128KB
    float* partials = (float*)(idx + N_Q);                          // 32KB

    k_normw<<<K_C, 256, 0, stream>>>(w, wh, wl, wnorm2);
    k_normx<<<N_Q / 4, 256, 0, stream>>>(x, xnorm, xh, xl);
    dim3 grid(K_C / 256, N_Q / 256);
    k_score<<<grid, 512, 0, stream>>>(xh, xl, wh, wl, wnorm2, pmin_part);
    k_argmin<<<N_Q / 256, 256, 0, stream>>>(pmin_part, idx);
    k_gather<<<N_Q / 4, 256, 0, stream>>>(x, w, xnorm, idx, qout, idxf, partials);
    k_loss<<<1, 256, 0, stream>>>(partials, loss);
}

// Round 4
// 958.803 us; speedup vs baseline: 1.1413x; 1.1413x over previous
//
#include <hip/hip_runtime.h>
#include <math.h>
#include <stdint.h>

#define N_Q 32768
#define K_C 8192
#define D_DIM 512
#define NSTEP 16        // K=512 / BK=32

typedef __attribute__((ext_vector_type(8))) short bf16x8;
typedef __attribute__((ext_vector_type(4))) float f32x4;

typedef const __attribute__((address_space(1))) void gv_t;
typedef __attribute__((address_space(3))) void lv_t;

static __device__ __forceinline__ void gl16(const void* g, void* l) {
    __builtin_amdgcn_global_load_lds((gv_t*)g, (lv_t*)l, 16, 0, 0);
}

static __device__ __forceinline__ unsigned short f2bf(float f) {
    unsigned u = __float_as_uint(f);
    unsigned r = u + 0x7fffu + ((u >> 16) & 1u);
    return (unsigned short)(r >> 16);
}
static __device__ __forceinline__ float bf2f(unsigned short h) {
    return __uint_as_float(((unsigned)h) << 16);
}

// ---------------- kernel 1: normalize emb rows -> wh/wl [k][d] bf16 + wnorm2[k]
__global__ void k_normw(const float* __restrict__ w, unsigned short* __restrict__ wh,
                        unsigned short* __restrict__ wl, float* __restrict__ wnorm2) {
    __shared__ float red[4];
    __shared__ float s_n;
    int k = blockIdx.x;
    int t = threadIdx.x;
    int lane = t & 63, wid = t >> 6;
    float v0 = w[(size_t)k * D_DIM + t];
    float v1 = w[(size_t)k * D_DIM + t + 256];
    float ss = fmaf(v0, v0, v1 * v1);
    for (int off = 32; off; off >>= 1) ss += __shfl_down(ss, off, 64);
    if (lane == 0) red[wid] = ss;
    __syncthreads();
    if (t == 0) s_n = fmaxf(sqrtf(red[0] + red[1] + red[2] + red[3]), 1e-12f);
    __syncthreads();
    float n = s_n;
    float a0 = v0 / n, a1 = v1 / n;
    unsigned short h0 = f2bf(a0), h1 = f2bf(a1);
    wh[(size_t)k * D_DIM + t] = h0;
    wh[(size_t)k * D_DIM + t + 256] = h1;
    wl[(size_t)k * D_DIM + t] = f2bf(a0 - bf2f(h0));
    wl[(size_t)k * D_DIM + t + 256] = f2bf(a1 - bf2f(h1));
    float s2 = fmaf(a0, a0, a1 * a1);
    for (int off = 32; off; off >>= 1) s2 += __shfl_down(s2, off, 64);
    __syncthreads();
    if (lane == 0) red[wid] = s2;
    __syncthreads();
    if (t == 0) wnorm2[k] = red[0] + red[1] + red[2] + red[3];
}

// ---------------- kernel 2: ||x_n|| per row + xh/xl [n][d] bf16
__global__ void k_normx(const float* __restrict__ x, float* __restrict__ xnorm,
                        unsigned short* __restrict__ xh, unsigned short* __restrict__ xl) {
    int wid = threadIdx.x >> 6, lane = threadIdx.x & 63;
    int n = blockIdx.x * 4 + wid;
    const float* xr = x + (size_t)n * D_DIM;
    float v[8];
    float ss = 0.f;
    #pragma unroll
    for (int i = 0; i < 8; ++i) {
        v[i] = xr[lane + i * 64];
        ss = fmaf(v[i], v[i], ss);
    }
    for (int off = 32; off; off >>= 1) ss += __shfl_down(ss, off, 64);
    ss = __shfl(ss, 0, 64);
    float nrm = fmaxf(sqrtf(ss), 1e-12f);
    if (lane == 0) xnorm[n] = nrm;
    #pragma unroll
    for (int i = 0; i < 8; ++i) {
        float a = v[i] / nrm;
        unsigned short h = f2bf(a);
        size_t o = (size_t)n * D_DIM + lane + i * 64;
        xh[o] = h;
        xl[o] = f2bf(a - bf2f(h));
    }
}

// ---------------- kernel 3: MFMA score + per-block argmin partials
// dist(n,k) = wnorm2[k] - 2*xn.wk ; dot in 3 bf16 passes (hh+hl+lh) with
// FRAGMENT REUSE: read Ah/Al/Bh/Bl frags once, 3 MFMAs per (m,n) pair.
// Block 256x256, BK=32, 512 thr = 8 waves (2M x 4N), per-wave 128x64.
// LDS: double buffer x 4 regions (Ah,Al,Bh,Bl; 256 rows x 32 d) = 2 x 64KB.
// Chunk swizzle phys = r*4 + (g ^ ((r>>1)&3))  (0 conflicts measured, round 2).
// Schedule: stage t+1 at TOP of step t -> 96 MFMA/wave -> single __syncthreads
// (its vmcnt(0) drain waits on ~930-cycle-old loads => free).
__global__ __launch_bounds__(512, 2) void k_score(
    const unsigned short* __restrict__ xh, const unsigned short* __restrict__ xl,
    const unsigned short* __restrict__ wh, const unsigned short* __restrict__ wl,
    const float* __restrict__ wnorm2, unsigned long long* __restrict__ pmin_part)
{
    __shared__ __align__(16) char lds[131072];
    int tid = threadIdx.x;
    int lane = tid & 63, wid = tid >> 6;
    int wm = wid >> 2, wn = wid & 3;
    int c15 = lane & 15, g = lane >> 4;

    // XCD-chunked bijective swizzle (4096 blocks, 4096%8==0):
    // XCD i owns logical ids [i*512,(i+1)*512) -> kt = id>>7 constant per XCD
    // chunk => 2MB W-slice L2-resident per XCD.
    int bid = blockIdx.x;
    int swz = (bid & 7) * 512 + (bid >> 3);
    int ktile = swz >> 7;           // 0..31
    int ntile = swz & 127;          // 0..127
    int k0 = ktile * 256;
    int n0 = ntile * 256;

    // fragment LDS byte offsets within a region
    int aoff[8], boff[4];
    #pragma unroll
    for (int m = 0; m < 8; ++m) {
        int r = wm * 128 + m * 16 + c15;
        aoff[m] = (r * 4 + (g ^ ((r >> 1) & 3))) * 16;
    }
    #pragma unroll
    for (int n = 0; n < 4; ++n) {
        int r = wn * 64 + n * 16 + c15;
        boff[n] = (r * 4 + (g ^ ((r >> 1) & 3))) * 16;
    }

    // staging: thread stages phys chunks tid (rows 0-127) and 512+tid (rows 128-255)
    int rs = tid >> 2;
    int gs = (tid & 3) ^ ((tid >> 3) & 3);
    size_t offA = (size_t)(n0 + rs) * D_DIM + gs * 8;
    size_t offB = (size_t)(k0 + rs) * D_DIM + gs * 8;

    f32x4 acc[8][4];
    #pragma unroll
    for (int m = 0; m < 8; ++m)
        #pragma unroll
        for (int n = 0; n < 4; ++n) acc[m][n] = (f32x4){0.f, 0.f, 0.f, 0.f};

    // prologue: stage step 0 into buf0
    {
        char* nb = lds + tid * 16;
        gl16(xh + offA, nb);
        gl16(xh + offA + 128 * D_DIM, nb + 8192);
        gl16(xl + offA, nb + 16384);
        gl16(xl + offA + 128 * D_DIM, nb + 24576);
        gl16(wh + offB, nb + 32768);
        gl16(wh + offB + 128 * D_DIM, nb + 40960);
        gl16(wl + offB, nb + 49152);
        gl16(wl + offB + 128 * D_DIM, nb + 57344);
    }
    __syncthreads();

    for (int t = 0; t < NSTEP; ++t) {
        // ---- stage step t+1 into the other buffer (issued early; latency
        //      hidden under this step's 96 MFMAs)
        if (t < NSTEP - 1) {
            int dd = (t + 1) * 32;
            char* nb = lds + (((t + 1) & 1) ? 65536 : 0) + tid * 16;
            gl16(xh + offA + dd, nb);
            gl16(xh + offA + dd + 128 * D_DIM, nb + 8192);
            gl16(xl + offA + dd, nb + 16384);
            gl16(xl + offA + dd + 128 * D_DIM, nb + 24576);
            gl16(wh + offB + dd, nb + 32768);
            gl16(wh + offB + dd + 128 * D_DIM, nb + 40960);
            gl16(wl + offB + dd, nb + 49152);
            gl16(wl + offB + dd + 128 * D_DIM, nb + 57344);
        }
        const char* cb = lds + ((t & 1) ? 65536 : 0);

        // B fragments: read once, held (32 VGPR)
        bf16x8 bh[4], bl[4];
        #pragma unroll
        for (int n = 0; n < 4; ++n) {
            bh[n] = *(const bf16x8*)(cb + 32768 + boff[n]);
            bl[n] = *(const bf16x8*)(cb + 49152 + boff[n]);
        }
        // stream A fragments; 3-product reuse per (m,n)
        #pragma unroll
        for (int m = 0; m < 8; ++m) {
            bf16x8 ah = *(const bf16x8*)(cb + aoff[m]);
            bf16x8 al = *(const bf16x8*)(cb + 16384 + aoff[m]);
            #pragma unroll
            for (int n = 0; n < 4; ++n) {
                acc[m][n] = __builtin_amdgcn_mfma_f32_16x16x32_bf16(ah, bh[n], acc[m][n], 0, 0, 0);
                acc[m][n] = __builtin_amdgcn_mfma_f32_16x16x32_bf16(ah, bl[n], acc[m][n], 0, 0, 0);
                acc[m][n] = __builtin_amdgcn_mfma_f32_16x16x32_bf16(al, bh[n], acc[m][n], 0, 0, 0);
            }
        }
        __syncthreads();   // drains vmcnt (old loads) + lgkm; flips buffer
    }

    // epilogue: dist = wnorm2[k] - 2*dot ; per-row argmin, wn-combined in LDS
    float w2[4];
    #pragma unroll
    for (int n = 0; n < 4; ++n) w2[n] = wnorm2[k0 + wn * 64 + n * 16 + c15];

    unsigned long long* scr = (unsigned long long*)lds;   // 256 rows x 4 wn = 8KB
    #pragma unroll
    for (int m = 0; m < 8; ++m) {
        #pragma unroll
        for (int reg = 0; reg < 4; ++reg) {
            float bv = INFINITY;
            int bk = 0x7fffffff;
            #pragma unroll
            for (int n = 0; n < 4; ++n) {
                float v = fmaf(-2.f, acc[m][n][reg], w2[n]);
                int kk = k0 + wn * 64 + n * 16 + c15;
                if (v < bv || (v == bv && kk < bk)) { bv = v; bk = kk; }
            }
            for (int off = 8; off; off >>= 1) {
                float v2 = __shfl_xor(bv, off, 16);
                int k2 = __shfl_xor(bk, off, 16);
                if (v2 < bv || (v2 == bv && k2 < bk)) { bv = v2; bk = k2; }
            }
            if (c15 == 0) {
                int row = wm * 128 + m * 16 + g * 4 + reg;
                unsigned ub = __float_as_uint(bv);
                ub = (ub & 0x80000000u) ? ~ub : (ub | 0x80000000u);
                scr[row * 4 + wn] = ((unsigned long long)ub << 32) | (unsigned)bk;
            }
        }
    }
    __syncthreads();
    if (tid < 256) {
        unsigned long long v = scr[tid * 4];
        #pragma unroll
        for (int j = 1; j < 4; ++j) {
            unsigned long long u = scr[tid * 4 + j];
            if (u < v) v = u;
        }
        pmin_part[(size_t)ktile * N_Q + n0 + tid] = v;
    }
}

// ---------------- kernel 4: final argmin reduce over the 32 code-tiles
__global__ void k_argmin(const unsigned long long* __restrict__ part, int* __restrict__ idx) {
    int n = blockIdx.x * 256 + threadIdx.x;
    unsigned long long v = part[n];
    #pragma unroll 4
    for (int j = 1; j < 32; ++j) {
        unsigned long long u = part[(size_t)j * N_Q + n];
        if (u < v) v = u;
    }
    idx[n] = (int)(unsigned)(v & 0xffffffffull);
}

// ---------------- kernel 5: gather quantized rows, write output + idxf, loss partials
__global__ void k_gather(const float* __restrict__ x, const float* __restrict__ emb,
                         const float* __restrict__ xnorm, const int* __restrict__ idx,
                         float* __restrict__ qout, float* __restrict__ idxf,
                         float* __restrict__ partials) {
    __shared__ float red[4];
    int t = threadIdx.x, lane = t & 63, wid = t >> 6;
    int n = blockIdx.x * 4 + wid;
    int k = idx[n];
    const float* er = emb + (size_t)k * D_DIM + lane * 8;
    float4 e0 = *(const float4*)er;
    float4 e1 = *(const float4*)(er + 4);
    float ss = e0.x * e0.x + e0.y * e0.y + e0.z * e0.z + e0.w * e0.w
             + e1.x * e1.x + e1.y * e1.y + e1.z * e1.z + e1.w * e1.w;
    for (int off = 32; off; off >>= 1) ss += __shfl_down(ss, off, 64);
    ss = __shfl(ss, 0, 64);
    float nn = fmaxf(sqrtf(ss), 1e-12f);
    float4 q0, q1;
    q0.x = e0.x / nn; q0.y = e0.y / nn; q0.z = e0.z / nn; q0.w = e0.w / nn;
    q1.x = e1.x / nn; q1.y = e1.y / nn; q1.z = e1.z / nn; q1.w = e1.w / nn;

    const float* xr = x + (size_t)n * D_DIM + lane * 8;
    float4 x0 = *(const float4*)xr;
    float4 x1 = *(const float4*)(xr + 4);
    float xn = xnorm[n];
    float d0 = x0.x / xn - q0.x, d1 = x0.y / xn - q0.y;
    float d2 = x0.z / xn - q0.z, d3 = x0.w / xn - q0.w;
    float d4 = x1.x / xn - q1.x, d5 = x1.y / xn - q1.y;
    float d6 = x1.z / xn - q1.z, d7 = x1.w / xn - q1.w;
    float ds = d0 * d0 + d1 * d1 + d2 * d2 + d3 * d3
             + d4 * d4 + d5 * d5 + d6 * d6 + d7 * d7;

    float* qo = qout + (size_t)n * D_DIM + lane * 8;
    *(float4*)qo = q0;
    *(float4*)(qo + 4) = q1;
    if (lane == 0) idxf[n] = (float)k;

    for (int off = 32; off; off >>= 1) ds += __shfl_down(ds, off, 64);
    if (lane == 0) red[wid] = ds;
    __syncthreads();
    if (t == 0) partials[blockIdx.x] = red[0] + red[1] + red[2] + red[3];
}

// ---------------- kernel 6: deterministic final loss reduction
__global__ void k_loss(const float* __restrict__ partials, float* __restrict__ out_loss) {
    __shared__ float red[4];
    int t = threadIdx.x, lane = t & 63, wid = t >> 6;
    float s = 0.f;
    for (int i = t; i < 8192; i += 256) s += partials[i];
    for (int off = 32; off; off >>= 1) s += __shfl_down(s, off, 64);
    if (lane == 0) red[wid] = s;
    __syncthreads();
    if (t == 0)
        out_loss[0] = (red[0] + red[1] + red[2] + red[3]) * (1.25f / ((float)N_Q * (float)D_DIM));
}

extern "C" void kernel_launch(void* const* d_in, const int* in_sizes, int n_in,
                              void* d_out, int out_size, void* d_ws, size_t ws_size,
                              hipStream_t stream) {
    (void)in_sizes; (void)n_in; (void)out_size; (void)ws_size;
    const float* x = (const float*)d_in[0];
    const float* w = (const float*)d_in[1];

    float* out = (float*)d_out;
    float* qout = out;                                  // N*D f32
    float* loss = out + (size_t)N_Q * D_DIM;            // 1
    float* idxf = loss + 1;                             // N

    // xh/xl scratch lives in the qout region (exactly 2*N*D shorts),
    // consumed by k_score, then overwritten by k_gather's final output.
    unsigned short* xh = (unsigned short*)qout;         // N*D shorts
    unsigned short* xl = xh + (size_t)N_Q * D_DIM;      // N*D shorts

    char* ws = (char*)d_ws;
    unsigned short* wh = (unsigned short*)ws;                       // 8MB
    unsigned short* wl = wh + (size_t)K_C * D_DIM;                  // 8MB
    float* wnorm2 = (float*)(wl + (size_t)K_C * D_DIM);             // 32KB
    float* xnorm = wnorm2 + K_C;                                    // 128KB
    unsigned long long* pmin_part = (unsigned long long*)(xnorm + N_Q);  // 32*N u64 = 8MB
    int* idx = (int*)(pmin_part + (size_t)32 * N_Q);                // 128KB
    float* partials = (float*)(idx + N_Q);                          // 32KB

    k_normw<<<K_C, 256, 0, stream>>>(w, wh, wl, wnorm2);
    k_normx<<<N_Q / 4, 256, 0, stream>>>(x, xnorm, xh, xl);
    k_score<<<4096, 512, 0, stream>>>(xh, xl, wh, wl, wnorm2, pmin_part);
    k_argmin<<<N_Q / 256, 256, 0, stream>>>(pmin_part, idx);
    k_gather<<<N_Q / 4, 256, 0, stream>>>(x, w, xnorm, idx, qout, idxf, partials);
    k_loss<<<1, 256, 0, stream>>>(partials, loss);
}